// Round 11
// baseline (91.591 us; speedup 1.0000x reference)
//
#include <hip/hip_runtime.h>

// Mixture-of-Tastes forward, MFMA main kernel (2 users/wave) — ATTRIBUTION
// PROBE ROUND: mot_mfma2_kernel is launched TWICE with identical arguments.
// It is idempotent (reads cnt/sve, writes identical out[eid] values), so
// correctness and determinism are unaffected; dur_us(R11) - dur_us(R10)
// measures the main kernel's true in-graph (warm) cost, which the rocprof
// top-5 table cannot show (it is flooded by ~58us 400MB d_ws poison fills).
//
//   zero:    cnt[NB]+ovfMeta = 0
//   scatter: fixed-cap user buckets (cap=64) + overflow list
//   main x2: one wave64 per TWO users; per 16-edge tile one
//            v_mfma_f32_16x16x32_f16 -> 8 logits + 8 scores.

#define MOT_CAP     64
#define MOT_OVF_CAP 4096

using half8 = __attribute__((ext_vector_type(8))) _Float16;
using f32x4 = __attribute__((ext_vector_type(4))) float;

__global__ void mot_zero_kernel(int4* __restrict__ p, int n4) {
    const int i = blockIdx.x * 256 + (int)threadIdx.x;
    if (i < n4) p[i] = make_int4(0, 0, 0, 0);
}

// fp32 divergent-u per-edge score (overflow path only; rare).
__device__ __forceinline__ float mot_score_div(const float* __restrict__ Ar,
                                               const float* __restrict__ Tr,
                                               const float4* __restrict__ Ep) {
    float4 ek[8];
    #pragma unroll
    for (int k4 = 0; k4 < 8; ++k4) ek[k4] = Ep[k4];
    float num = 0.f, den = 0.f;
    #pragma unroll
    for (int m = 0; m < 8; ++m) {
        float l = 0.f, s = 0.f;
        #pragma unroll
        for (int k4 = 0; k4 < 8; ++k4) {
            const float4 a = *(const float4*)(Ar + m * 32 + k4 * 4);
            const float4 t = *(const float4*)(Tr + m * 32 + k4 * 4);
            const float4 e = ek[k4];
            l = fmaf(a.x, e.x, l); l = fmaf(a.y, e.y, l);
            l = fmaf(a.z, e.z, l); l = fmaf(a.w, e.w, l);
            s = fmaf(t.x, e.x, s); s = fmaf(t.y, e.y, s);
            s = fmaf(t.z, e.z, s); s = fmaf(t.w, e.w, s);
        }
        const float ex = __expf(l);
        den += ex;
        num = fmaf(ex, s, num);
    }
    return num / den;
}

__global__ void mot_scatter_kernel(const int4* __restrict__ edge2,
                                   int* __restrict__ cnt,
                                   int* __restrict__ ovfMeta,
                                   int* __restrict__ ovf,
                                   int2* __restrict__ sve,
                                   int nPairs, int nEdges) {
    const int i = blockIdx.x * 256 + (int)threadIdx.x;
    if (i < nPairs) {
        const int4 q = edge2[i];   // edges (q.x,q.y) eid=2i and (q.z,q.w) eid=2i+1
        int pos = atomicAdd(&cnt[q.x], 1);
        if (pos < MOT_CAP) sve[(size_t)q.x * MOT_CAP + pos] = make_int2(q.y, 2 * i);
        else { int o = atomicAdd(ovfMeta, 1); if (o < MOT_OVF_CAP) ovf[o] = 2 * i; }
        pos = atomicAdd(&cnt[q.z], 1);
        if (pos < MOT_CAP) sve[(size_t)q.z * MOT_CAP + pos] = make_int2(q.w, 2 * i + 1);
        else { int o = atomicAdd(ovfMeta, 1); if (o < MOT_OVF_CAP) ovf[o] = 2 * i + 1; }
    } else if (i == nPairs && (nEdges & 1)) {
        const int2 e = ((const int2*)edge2)[nEdges - 1];
        int pos = atomicAdd(&cnt[e.x], 1);
        if (pos < MOT_CAP) sve[(size_t)e.x * MOT_CAP + pos] = make_int2(e.y, nEdges - 1);
        else { int o = atomicAdd(ovfMeta, 1); if (o < MOT_OVF_CAP) ovf[o] = nEdges - 1; }
    }
}

__device__ __forceinline__ half8 mot_load_afrag(const float* __restrict__ attn_emb,
                                                const float* __restrict__ taste_emb,
                                                int u, int row, int k0) {
    const float* rowp = (row < 8)
        ? attn_emb  + (size_t)u * 256 + row * 32 + k0
        : taste_emb + (size_t)u * 256 + (row - 8) * 32 + k0;
    const float4 r0 = *(const float4*)rowp;
    const float4 r1 = *(const float4*)(rowp + 4);
    half8 af;
    af[0] = (_Float16)r0.x; af[1] = (_Float16)r0.y;
    af[2] = (_Float16)r0.z; af[3] = (_Float16)r0.w;
    af[4] = (_Float16)r1.x; af[5] = (_Float16)r1.y;
    af[6] = (_Float16)r1.z; af[7] = (_Float16)r1.w;
    return af;
}

__global__ __launch_bounds__(256, 6) void mot_mfma2_kernel(
    const int2* __restrict__ edge,
    const float* __restrict__ taste_emb,    // [N_USERS][256]
    const float* __restrict__ attn_emb,     // [N_USERS][256]
    const float4* __restrict__ movie_emb,   // [N_MOVIES][8] float4
    const float* __restrict__ user_bias,
    const float* __restrict__ movie_bias,
    const int* __restrict__ cnt,
    const int2* __restrict__ sve,
    const int* __restrict__ ovfMeta,
    const int* __restrict__ ovf,
    float* __restrict__ out,
    int nUsers, int mainBlocks)
{
    const int tid  = (int)threadIdx.x;
    const int lane = tid & 63;

    if ((int)blockIdx.x < mainBlocks) {
        const int u0 = ((int)blockIdx.x * 4 + (tid >> 6)) * 2;  // wave = 2 users
        const int u1 = u0 + 1;
        if (u0 >= nUsers) return;

        const int row = lane & 15;     // A row / C col
        const int kq  = lane >> 4;     // k-quarter 0..3
        const int k0  = kq * 8;
        const int hi  = kq & 1;

        int n0 = cnt[u0]; n0 = n0 > MOT_CAP ? MOT_CAP : n0;
        int n1 = (u1 < nUsers) ? cnt[u1] : 0; n1 = n1 > MOT_CAP ? MOT_CAP : n1;
        const half8 af0 = mot_load_afrag(attn_emb, taste_emb, u0, row, k0);
        const half8 af1 = mot_load_afrag(attn_emb, taste_emb, u1, row, k0);
        const float ub0 = user_bias[u0];
        const float ub1 = user_bias[u1];
        const int2* __restrict__ b0 = sve + (size_t)u0 * MOT_CAP;
        const int2* __restrict__ b1 = sve + (size_t)u1 * MOT_CAP;

        int t0 = 0, t1 = 0;
        while (t0 < n0 || t1 < n1) {        // wave-uniform condition
            const bool d0 = t0 < n0, d1 = t1 < n1;

            int2 ve0 = make_int2(0, -1), ve1 = make_int2(0, -1);
            half8 bf0 = {}, bf1 = {};
            bool val0 = false, val1 = false;
            if (d0) {
                const int ei = t0 + row;
                val0 = ei < n0;
                if (val0) {
                    ve0 = b0[ei];
                    const float4* __restrict__ Ep = movie_emb + (size_t)ve0.x * 8;
                    const float4 e0 = Ep[kq * 2], e1 = Ep[kq * 2 + 1];
                    bf0[0] = (_Float16)e0.x; bf0[1] = (_Float16)e0.y;
                    bf0[2] = (_Float16)e0.z; bf0[3] = (_Float16)e0.w;
                    bf0[4] = (_Float16)e1.x; bf0[5] = (_Float16)e1.y;
                    bf0[6] = (_Float16)e1.z; bf0[7] = (_Float16)e1.w;
                }
            }
            if (d1) {
                const int ei = t1 + row;
                val1 = ei < n1;
                if (val1) {
                    ve1 = b1[ei];
                    const float4* __restrict__ Ep = movie_emb + (size_t)ve1.x * 8;
                    const float4 e0 = Ep[kq * 2], e1 = Ep[kq * 2 + 1];
                    bf1[0] = (_Float16)e0.x; bf1[1] = (_Float16)e0.y;
                    bf1[2] = (_Float16)e0.z; bf1[3] = (_Float16)e0.w;
                    bf1[4] = (_Float16)e1.x; bf1[5] = (_Float16)e1.y;
                    bf1[6] = (_Float16)e1.z; bf1[7] = (_Float16)e1.w;
                }
            }

            #pragma unroll
            for (int g = 0; g < 2; ++g) {
                const bool dg = g ? d1 : d0;
                if (!dg) continue;
                const half8 af = g ? af1 : af0;
                const half8 bf = g ? bf1 : bf0;
                const bool val = g ? val1 : val0;
                const int2 ve = g ? ve1 : ve0;
                const float ub = g ? ub1 : ub0;

                f32x4 c = {0.f, 0.f, 0.f, 0.f};
                c = __builtin_amdgcn_mfma_f32_16x16x32_f16(af, bf, c, 0, 0, 0);
                // c[j] = C[kq*4+j][col]: q0=L0-3, q1=L4-7, q2=S0-3, q3=S4-7.

                const float o0 = __shfl_xor(c[0], 16);
                const float o1 = __shfl_xor(c[1], 16);
                const float o2 = __shfl_xor(c[2], 16);
                const float o3 = __shfl_xor(c[3], 16);
                float v0 = hi ? o0 : c[0], v1 = hi ? o1 : c[1];
                float v2 = hi ? o2 : c[2], v3 = hi ? o3 : c[3];
                float v4 = hi ? c[0] : o0, v5 = hi ? c[1] : o1;
                float v6 = hi ? c[2] : o2, v7 = hi ? c[3] : o3;
                const float w0 = __shfl_xor(v0, 32), w1 = __shfl_xor(v1, 32);
                const float w2 = __shfl_xor(v2, 32), w3 = __shfl_xor(v3, 32);
                const float w4 = __shfl_xor(v4, 32), w5 = __shfl_xor(v5, 32);
                const float w6 = __shfl_xor(v6, 32), w7 = __shfl_xor(v7, 32);

                if (kq == 0 && val) {
                    // lanes 0-15: v = logits[0..7], w = scores[0..7].
                    // |logit| < ~0.05: unstabilized softmax is exact.
                    float den = 0.f, num = 0.f;
                    const float e0x = __expf(v0); den += e0x; num = fmaf(e0x, w0, num);
                    const float e1x = __expf(v1); den += e1x; num = fmaf(e1x, w1, num);
                    const float e2x = __expf(v2); den += e2x; num = fmaf(e2x, w2, num);
                    const float e3x = __expf(v3); den += e3x; num = fmaf(e3x, w3, num);
                    const float e4x = __expf(v4); den += e4x; num = fmaf(e4x, w4, num);
                    const float e5x = __expf(v5); den += e5x; num = fmaf(e5x, w5, num);
                    const float e6x = __expf(v6); den += e6x; num = fmaf(e6x, w6, num);
                    const float e7x = __expf(v7); den += e7x; num = fmaf(e7x, w7, num);
                    out[ve.y] = num * __builtin_amdgcn_rcpf(den) + ub + movie_bias[ve.x];
                }
            }
            t0 += 16; t1 += 16;
        }
    } else {
        int oc = ovfMeta[0];
        if (oc > MOT_OVF_CAP) oc = MOT_OVF_CAP;
        const int oi = ((int)blockIdx.x - mainBlocks) * 256 + tid;
        if (oi < oc) {
            const int eid = ovf[oi];
            const int2 ed = edge[eid];
            out[eid] = mot_score_div(attn_emb  + (size_t)ed.x * 256,
                                     taste_emb + (size_t)ed.x * 256,
                                     movie_emb + (size_t)ed.y * 8)
                       + user_bias[ed.x] + movie_bias[ed.y];
        }
    }
}

// ---- flat fallback (no scratch needed) ----
__global__ __launch_bounds__(256, 4) void mot_flat_kernel(
    const int2* __restrict__ edge,
    const float4* __restrict__ taste_emb,
    const float4* __restrict__ attn_emb,
    const float4* __restrict__ movie_emb,
    const float* __restrict__ user_bias,
    const float* __restrict__ movie_bias,
    float* __restrict__ out,
    int nEdges)
{
    const int tid  = blockIdx.x * 256 + (int)threadIdx.x;
    const int eid  = tid >> 5;
    const int s    = tid & 31;
    if (eid >= nEdges) return;
    const int2 ed = edge[eid];
    const int u = ed.x, v = ed.y;
    const float4* Ap = attn_emb  + (size_t)u * 64;
    const float4* Tp = taste_emb + (size_t)u * 64;
    const float4* Ep = movie_emb + (size_t)v * 8;
    const float4 a0 = Ap[2 * s], a1 = Ap[2 * s + 1];
    const float4 t0 = Tp[2 * s], t1 = Tp[2 * s + 1];
    const int c = s & 3;
    const float4 e0 = Ep[2 * c], e1 = Ep[2 * c + 1];
    float lp = a0.x*e0.x + a0.y*e0.y + a0.z*e0.z + a0.w*e0.w
             + a1.x*e1.x + a1.y*e1.y + a1.z*e1.z + a1.w*e1.w;
    float sp = t0.x*e0.x + t0.y*e0.y + t0.z*e0.z + t0.w*e0.w
             + t1.x*e1.x + t1.y*e1.y + t1.z*e1.z + t1.w*e1.w;
    lp += __shfl_xor(lp, 1); lp += __shfl_xor(lp, 2);
    sp += __shfl_xor(sp, 1); sp += __shfl_xor(sp, 2);
    const float ex = __expf(lp);
    float den = ex, num = ex * sp;
    den += __shfl_xor(den, 4);  num += __shfl_xor(num, 4);
    den += __shfl_xor(den, 8);  num += __shfl_xor(num, 8);
    den += __shfl_xor(den, 16); num += __shfl_xor(num, 16);
    if (s == 0) out[eid] = num / den + user_bias[u] + movie_bias[v];
}

extern "C" void kernel_launch(void* const* d_in, const int* in_sizes, int n_in,
                              void* d_out, int out_size, void* d_ws, size_t ws_size,
                              hipStream_t stream) {
    const int2*   edge       = (const int2*)d_in[0];
    const float*  taste_emb  = (const float*)d_in[1];
    const float*  attn_emb   = (const float*)d_in[2];
    const float*  movie_emb  = (const float*)d_in[3];
    const float*  user_bias  = (const float*)d_in[4];
    const float*  movie_bias = (const float*)d_in[5];
    float*        out        = (float*)d_out;

    const int nEdges = in_sizes[0] / 2;     // edge is [B,2] int32
    const int NB     = in_sizes[3] / 32;    // id bound (20000)

    auto align256 = [](size_t x) { return (x + 255) & ~(size_t)255; };
    char* ws = (char*)d_ws;

    const size_t o_cnt  = 0;
    const size_t o_meta = align256((size_t)NB * 4);
    const size_t o_ovf  = o_meta + 256;
    const size_t o_sve  = align256(o_ovf + (size_t)MOT_OVF_CAP * 4);
    const size_t need   = o_sve + (size_t)NB * MOT_CAP * 8;

    if (ws_size < need) {
        const int blocks = (nEdges * 32 + 255) / 256;
        mot_flat_kernel<<<blocks, 256, 0, stream>>>(
            edge, (const float4*)taste_emb, (const float4*)attn_emb,
            (const float4*)movie_emb, user_bias, movie_bias, out, nEdges);
        return;
    }

    int*  cnt     = (int*)(ws + o_cnt);
    int*  ovfMeta = (int*)(ws + o_meta);
    int*  ovf     = (int*)(ws + o_ovf);
    int2* sve     = (int2*)(ws + o_sve);

    const int n4 = (int)(o_ovf / 16);
    mot_zero_kernel<<<(n4 + 255) / 256, 256, 0, stream>>>((int4*)ws, n4);

    const int nPairs  = nEdges / 2;
    const int sblocks = (nPairs + 1 + 255) / 256;
    mot_scatter_kernel<<<sblocks, 256, 0, stream>>>(
        (const int4*)edge, cnt, ovfMeta, ovf, sve, nPairs, nEdges);

    const int mainBlocks = (NB + 7) / 8;        // 2 users/wave, 4 waves/block
    const int ovfBlocks  = MOT_OVF_CAP / 256;

    // PROBE: launch main twice (idempotent). dur_us delta vs previous round
    // measures the main kernel's true in-graph (warm) cost.
    mot_mfma2_kernel<<<mainBlocks + ovfBlocks, 256, 0, stream>>>(
        edge, taste_emb, attn_emb, (const float4*)movie_emb,
        user_bias, movie_bias, cnt, sve, ovfMeta, ovf, out, NB, mainBlocks);
    mot_mfma2_kernel<<<mainBlocks + ovfBlocks, 256, 0, stream>>>(
        edge, taste_emb, attn_emb, (const float4*)movie_emb,
        user_bias, movie_bias, cnt, sve, ovfMeta, ovf, out, NB, mainBlocks);
}

// Round 12
// 65.745 us; speedup vs baseline: 1.3931x; 1.3931x over previous
//
#include <hip/hip_runtime.h>

// Mixture-of-Tastes forward, MFMA main with deep memory-level parallelism:
//   zero:    cnt[NB]+ovfMeta = 0
//   scatter: fixed-cap user buckets (cap=64) + overflow list
//   main:    wave64 = 2 users. ALL 4 tiles x 2 users fully unrolled:
//            16 bucket loads issue unpredicated (garbage clamped to movie 0,
//            output still predicated by ei<n), then 16 movie-row loads ->
//            ~24 outstanding VMEM/lane. R10/R11 probe showed main is COLD
//            each replay (62us cold vs 25us warm) at 0.94 TB/s = latency-
//            bound; R1 proved 3.65 TB/s gather with enough independent loads.
//   epilogue: per-quarter partial softmax: xor32 on c[0..3], 4 exps (lanes
//            0-31), xor16 combine -> 6 shuffles/tile vs 12.
// Per-edge output is order-independent -> deterministic despite atomic scatter.

#define MOT_CAP     64
#define MOT_OVF_CAP 4096

using half8 = __attribute__((ext_vector_type(8))) _Float16;
using f32x4 = __attribute__((ext_vector_type(4))) float;

__global__ void mot_zero_kernel(int4* __restrict__ p, int n4) {
    const int i = blockIdx.x * 256 + (int)threadIdx.x;
    if (i < n4) p[i] = make_int4(0, 0, 0, 0);
}

// fp32 divergent-u per-edge score (overflow path only; rare).
__device__ __forceinline__ float mot_score_div(const float* __restrict__ Ar,
                                               const float* __restrict__ Tr,
                                               const float4* __restrict__ Ep) {
    float4 ek[8];
    #pragma unroll
    for (int k4 = 0; k4 < 8; ++k4) ek[k4] = Ep[k4];
    float num = 0.f, den = 0.f;
    #pragma unroll
    for (int m = 0; m < 8; ++m) {
        float l = 0.f, s = 0.f;
        #pragma unroll
        for (int k4 = 0; k4 < 8; ++k4) {
            const float4 a = *(const float4*)(Ar + m * 32 + k4 * 4);
            const float4 t = *(const float4*)(Tr + m * 32 + k4 * 4);
            const float4 e = ek[k4];
            l = fmaf(a.x, e.x, l); l = fmaf(a.y, e.y, l);
            l = fmaf(a.z, e.z, l); l = fmaf(a.w, e.w, l);
            s = fmaf(t.x, e.x, s); s = fmaf(t.y, e.y, s);
            s = fmaf(t.z, e.z, s); s = fmaf(t.w, e.w, s);
        }
        const float ex = __expf(l);
        den += ex;
        num = fmaf(ex, s, num);
    }
    return num / den;
}

__global__ void mot_scatter_kernel(const int4* __restrict__ edge2,
                                   int* __restrict__ cnt,
                                   int* __restrict__ ovfMeta,
                                   int* __restrict__ ovf,
                                   int2* __restrict__ sve,
                                   int nPairs, int nEdges) {
    const int i = blockIdx.x * 256 + (int)threadIdx.x;
    if (i < nPairs) {
        const int4 q = edge2[i];   // edges (q.x,q.y) eid=2i and (q.z,q.w) eid=2i+1
        int pos = atomicAdd(&cnt[q.x], 1);
        if (pos < MOT_CAP) sve[(size_t)q.x * MOT_CAP + pos] = make_int2(q.y, 2 * i);
        else { int o = atomicAdd(ovfMeta, 1); if (o < MOT_OVF_CAP) ovf[o] = 2 * i; }
        pos = atomicAdd(&cnt[q.z], 1);
        if (pos < MOT_CAP) sve[(size_t)q.z * MOT_CAP + pos] = make_int2(q.w, 2 * i + 1);
        else { int o = atomicAdd(ovfMeta, 1); if (o < MOT_OVF_CAP) ovf[o] = 2 * i + 1; }
    } else if (i == nPairs && (nEdges & 1)) {
        const int2 e = ((const int2*)edge2)[nEdges - 1];
        int pos = atomicAdd(&cnt[e.x], 1);
        if (pos < MOT_CAP) sve[(size_t)e.x * MOT_CAP + pos] = make_int2(e.y, nEdges - 1);
        else { int o = atomicAdd(ovfMeta, 1); if (o < MOT_OVF_CAP) ovf[o] = nEdges - 1; }
    }
}

__device__ __forceinline__ half8 mot_load_afrag(const float* __restrict__ attn_emb,
                                                const float* __restrict__ taste_emb,
                                                int u, int row, int k0) {
    const float* rowp = (row < 8)
        ? attn_emb  + (size_t)u * 256 + row * 32 + k0
        : taste_emb + (size_t)u * 256 + (row - 8) * 32 + k0;
    const float4 r0 = *(const float4*)rowp;
    const float4 r1 = *(const float4*)(rowp + 4);
    half8 af;
    af[0] = (_Float16)r0.x; af[1] = (_Float16)r0.y;
    af[2] = (_Float16)r0.z; af[3] = (_Float16)r0.w;
    af[4] = (_Float16)r1.x; af[5] = (_Float16)r1.y;
    af[6] = (_Float16)r1.z; af[7] = (_Float16)r1.w;
    return af;
}

__global__ __launch_bounds__(256, 4) void mot_mfma4_kernel(
    const int2* __restrict__ edge,
    const float* __restrict__ taste_emb,    // [N_USERS][256]
    const float* __restrict__ attn_emb,     // [N_USERS][256]
    const float4* __restrict__ movie_emb,   // [N_MOVIES][8] float4
    const float* __restrict__ user_bias,
    const float* __restrict__ movie_bias,
    const int* __restrict__ cnt,
    const int2* __restrict__ sve,
    const int* __restrict__ ovfMeta,
    const int* __restrict__ ovf,
    float* __restrict__ out,
    int nUsers, int nMovies, int mainBlocks)
{
    const int tid  = (int)threadIdx.x;
    const int lane = tid & 63;

    if ((int)blockIdx.x < mainBlocks) {
        const int u0 = ((int)blockIdx.x * 4 + (tid >> 6)) * 2;  // wave = 2 users
        const int u1 = u0 + 1;
        if (u0 >= nUsers) return;

        const int row = lane & 15;     // A row / C col / edge slot within tile
        const int kq  = lane >> 4;     // k-quarter 0..3
        const int k0  = kq * 8;

        const int2* __restrict__ b0 = sve + (size_t)u0 * MOT_CAP;
        const int2* __restrict__ b1 = sve + (size_t)u1 * MOT_CAP;

        // ---- 16 independent bucket loads, unpredicated (max MLP) ----
        int2 ve0[4], ve1[4];
        #pragma unroll
        for (int T = 0; T < 4; ++T) ve0[T] = b0[T * 16 + row];
        #pragma unroll
        for (int T = 0; T < 4; ++T) ve1[T] = b1[T * 16 + row];

        // Wave-uniform scalar loads in parallel with the above.
        int n0 = cnt[u0]; n0 = n0 > MOT_CAP ? MOT_CAP : n0;
        int n1 = (u1 < nUsers) ? cnt[u1] : 0; n1 = n1 > MOT_CAP ? MOT_CAP : n1;
        const float ub0 = user_bias[u0];
        const float ub1 = user_bias[u1];

        // A-frags (independent of everything above).
        const half8 af0 = mot_load_afrag(attn_emb, taste_emb, u0, row, k0);
        const half8 af1 = mot_load_afrag(attn_emb, taste_emb, u1, row, k0);

        // ---- 16 movie-row loads (each 2x float4), clamped garbage -> row 0 ----
        half8 bf0[4], bf1[4];
        #pragma unroll
        for (int g2 = 0; g2 < 2; ++g2) {
            const int2* ve = g2 ? ve1 : ve0;
            half8* bf = g2 ? bf1 : bf0;
            #pragma unroll
            for (int T = 0; T < 4; ++T) {
                const int vx = ((unsigned)ve[T].x < (unsigned)nMovies) ? ve[T].x : 0;
                const float4* __restrict__ Ep = movie_emb + (size_t)vx * 8;
                const float4 e0 = Ep[kq * 2], e1 = Ep[kq * 2 + 1];
                half8 b;
                b[0] = (_Float16)e0.x; b[1] = (_Float16)e0.y;
                b[2] = (_Float16)e0.z; b[3] = (_Float16)e0.w;
                b[4] = (_Float16)e1.x; b[5] = (_Float16)e1.y;
                b[6] = (_Float16)e1.z; b[7] = (_Float16)e1.w;
                bf[T] = b;
            }
        }

        // ---- compute: 8 MFMAs + cheap epilogues ----
        #pragma unroll
        for (int T = 0; T < 4; ++T) {
            #pragma unroll
            for (int g = 0; g < 2; ++g) {
                const int n = g ? n1 : n0;
                if (T * 16 >= n) continue;          // wave-uniform skip
                const half8 af = g ? af1 : af0;
                const half8 bf = g ? bf0[0] : bf0[0]; // placeholder avoided below
                (void)bf;
                const half8 bfx = g ? bf1[T] : bf0[T];
                const int2 ve = g ? ve1[T] : ve0[T];
                const float ub = g ? ub1 : ub0;

                f32x4 c = {0.f, 0.f, 0.f, 0.f};
                c = __builtin_amdgcn_mfma_f32_16x16x32_f16(af, bfx, c, 0, 0, 0);
                // c[j] = C[kq*4+j][col]: kq0=L0-3, kq1=L4-7, kq2=S0-3, kq3=S4-7.

                // xor32 brings S to the L-quarters (kq0<->kq2, kq1<->kq3).
                const float s0 = __shfl_xor(c[0], 32);
                const float s1 = __shfl_xor(c[1], 32);
                const float s2 = __shfl_xor(c[2], 32);
                const float s3 = __shfl_xor(c[3], 32);
                // Lanes 0-31: partial softmax over this quarter's 4 logits.
                // |logit| < ~0.05: unstabilized softmax is exact.
                const float e0x = __expf(c[0]);
                const float e1x = __expf(c[1]);
                const float e2x = __expf(c[2]);
                const float e3x = __expf(c[3]);
                float den = e0x + e1x + e2x + e3x;
                float num = e0x * s0;
                num = fmaf(e1x, s1, num);
                num = fmaf(e2x, s2, num);
                num = fmaf(e3x, s3, num);
                // xor16 combines kq0+kq1 partials.
                den += __shfl_xor(den, 16);
                num += __shfl_xor(num, 16);

                if (kq == 0) {
                    const int ei = T * 16 + row;
                    if (ei < n)
                        out[ve.y] = num * __builtin_amdgcn_rcpf(den) + ub
                                    + movie_bias[ve.x];
                }
            }
        }
    } else {
        // Overflow edges (normally zero): fp32 divergent-u compute.
        int oc = ovfMeta[0];
        if (oc > MOT_OVF_CAP) oc = MOT_OVF_CAP;
        const int oi = ((int)blockIdx.x - mainBlocks) * 256 + tid;
        if (oi < oc) {
            const int eid = ovf[oi];
            const int2 ed = edge[eid];
            out[eid] = mot_score_div(attn_emb  + (size_t)ed.x * 256,
                                     taste_emb + (size_t)ed.x * 256,
                                     movie_emb + (size_t)ed.y * 8)
                       + user_bias[ed.x] + movie_bias[ed.y];
        }
    }
}

// ---- flat fallback (no scratch needed) ----
__global__ __launch_bounds__(256, 4) void mot_flat_kernel(
    const int2* __restrict__ edge,
    const float4* __restrict__ taste_emb,
    const float4* __restrict__ attn_emb,
    const float4* __restrict__ movie_emb,
    const float* __restrict__ user_bias,
    const float* __restrict__ movie_bias,
    float* __restrict__ out,
    int nEdges)
{
    const int tid  = blockIdx.x * 256 + (int)threadIdx.x;
    const int eid  = tid >> 5;
    const int s    = tid & 31;
    if (eid >= nEdges) return;
    const int2 ed = edge[eid];
    const int u = ed.x, v = ed.y;
    const float4* Ap = attn_emb  + (size_t)u * 64;
    const float4* Tp = taste_emb + (size_t)u * 64;
    const float4* Ep = movie_emb + (size_t)v * 8;
    const float4 a0 = Ap[2 * s], a1 = Ap[2 * s + 1];
    const float4 t0 = Tp[2 * s], t1 = Tp[2 * s + 1];
    const int c = s & 3;
    const float4 e0 = Ep[2 * c], e1 = Ep[2 * c + 1];
    float lp = a0.x*e0.x + a0.y*e0.y + a0.z*e0.z + a0.w*e0.w
             + a1.x*e1.x + a1.y*e1.y + a1.z*e1.z + a1.w*e1.w;
    float sp = t0.x*e0.x + t0.y*e0.y + t0.z*e0.z + t0.w*e0.w
             + t1.x*e1.x + t1.y*e1.y + t1.z*e1.z + t1.w*e1.w;
    lp += __shfl_xor(lp, 1); lp += __shfl_xor(lp, 2);
    sp += __shfl_xor(sp, 1); sp += __shfl_xor(sp, 2);
    const float ex = __expf(lp);
    float den = ex, num = ex * sp;
    den += __shfl_xor(den, 4);  num += __shfl_xor(num, 4);
    den += __shfl_xor(den, 8);  num += __shfl_xor(num, 8);
    den += __shfl_xor(den, 16); num += __shfl_xor(num, 16);
    if (s == 0) out[eid] = num / den + user_bias[u] + movie_bias[v];
}

extern "C" void kernel_launch(void* const* d_in, const int* in_sizes, int n_in,
                              void* d_out, int out_size, void* d_ws, size_t ws_size,
                              hipStream_t stream) {
    const int2*   edge       = (const int2*)d_in[0];
    const float*  taste_emb  = (const float*)d_in[1];
    const float*  attn_emb   = (const float*)d_in[2];
    const float*  movie_emb  = (const float*)d_in[3];
    const float*  user_bias  = (const float*)d_in[4];
    const float*  movie_bias = (const float*)d_in[5];
    float*        out        = (float*)d_out;

    const int nEdges = in_sizes[0] / 2;     // edge is [B,2] int32
    const int NB     = in_sizes[3] / 32;    // id bound (20000)

    auto align256 = [](size_t x) { return (x + 255) & ~(size_t)255; };
    char* ws = (char*)d_ws;

    const size_t o_cnt  = 0;
    const size_t o_meta = align256((size_t)NB * 4);
    const size_t o_ovf  = o_meta + 256;
    const size_t o_sve  = align256(o_ovf + (size_t)MOT_OVF_CAP * 4);
    const size_t need   = o_sve + (size_t)NB * MOT_CAP * 8;

    if (ws_size < need) {
        const int blocks = (nEdges * 32 + 255) / 256;
        mot_flat_kernel<<<blocks, 256, 0, stream>>>(
            edge, (const float4*)taste_emb, (const float4*)attn_emb,
            (const float4*)movie_emb, user_bias, movie_bias, out, nEdges);
        return;
    }

    int*  cnt     = (int*)(ws + o_cnt);
    int*  ovfMeta = (int*)(ws + o_meta);
    int*  ovf     = (int*)(ws + o_ovf);
    int2* sve     = (int2*)(ws + o_sve);

    const int n4 = (int)(o_ovf / 16);
    mot_zero_kernel<<<(n4 + 255) / 256, 256, 0, stream>>>((int4*)ws, n4);

    const int nPairs  = nEdges / 2;
    const int sblocks = (nPairs + 1 + 255) / 256;
    mot_scatter_kernel<<<sblocks, 256, 0, stream>>>(
        (const int4*)edge, cnt, ovfMeta, ovf, sve, nPairs, nEdges);

    const int mainBlocks = (NB + 7) / 8;        // 2 users/wave, 4 waves/block
    const int ovfBlocks  = MOT_OVF_CAP / 256;
    mot_mfma4_kernel<<<mainBlocks + ovfBlocks, 256, 0, stream>>>(
        edge, taste_emb, attn_emb, (const float4*)movie_emb,
        user_bias, movie_bias, cnt, sve, ovfMeta, ovf, out, NB, NB, mainBlocks);
}